// Round 6
// baseline (8574.492 us; speedup 1.0000x reference)
//
#include <hip/hip_runtime.h>

#define TW    10000
#define EMBD  100
#define SEQ   80
#define U     512
#define BATCH 2048
#define RPB   16
#define NBLK  (BATCH / RPB)   // 128 blocks
#define NTHR  1024            // 16 waves/block

typedef short short8 __attribute__((ext_vector_type(8)));
typedef float f32x4 __attribute__((ext_vector_type(4)));

static __device__ __forceinline__ unsigned short f2bf(float f){
  unsigned int u = __float_as_uint(f);
  u += 0x7fffu + ((u >> 16) & 1u);   // RNE
  return (unsigned short)(u >> 16);
}
static __device__ __forceinline__ float bf2f(unsigned short h){
  return __uint_as_float(((unsigned int)h) << 16);
}
static __device__ __forceinline__ float fast_tanh(float x){
  float e = __expf(2.0f * x);        // inf-safe: saturates to +-1
  return 1.0f - 2.0f / (e + 1.0f);
}

// ---------------- proj[w][n] = b0[n] + sum_e emb[w][e] * Wx0[e][n] ----------------
__global__ void proj_kernel(const float* __restrict__ emb, const float* __restrict__ Wx0,
                            const float* __restrict__ b0, float* __restrict__ proj){
  __shared__ float es[16][EMBD];
  const int w0 = blockIdx.x * 16;
  for (int i = threadIdx.x; i < 16 * EMBD; i += 256)
    es[i / EMBD][i % EMBD] = emb[(size_t)w0 * EMBD + i];
  __syncthreads();
  const int n = threadIdx.x;   // cols n and n+256
  float accA[16], accB[16];
#pragma unroll
  for (int wi = 0; wi < 16; ++wi){ accA[wi] = 0.0f; accB[wi] = 0.0f; }
  for (int e = 0; e < EMBD; ++e){
    const float wv0 = Wx0[(size_t)e * U + n];
    const float wv1 = Wx0[(size_t)e * U + n + 256];
#pragma unroll
    for (int wi = 0; wi < 16; ++wi){
      accA[wi] += es[wi][e] * wv0;
      accB[wi] += es[wi][e] * wv1;
    }
  }
  const float bb0 = b0[n], bb1 = b0[n + 256];
  for (int wi = 0; wi < 16; ++wi){
    proj[(size_t)(w0 + wi) * U + n]       = accA[wi] + bb0;
    proj[(size_t)(w0 + wi) * U + n + 256] = accB[wi] + bb1;
  }
}

// ---------------- dst[n][kOff + k] = bf16(src[k][n]),  src is [K][N] f32 ----------------
__global__ void transpose_bf16(const float* __restrict__ src, unsigned short* __restrict__ dst,
                               int K, int N, int dstLd, int kOff){
  const int idx = blockIdx.x * 256 + threadIdx.x;
  if (idx >= K * N) return;
  const int k = idx % K, n = idx / K;
  dst[(size_t)n * dstLd + kOff + k] = f2bf(src[(size_t)k * N + n]);
}

// One GEMM segment: 4-deep rotating named-register prefetch of B (nt loads),
// A from swizzled state LDS. Payload = 8 short8 = 32 VGPRs (no spill).
// Compiler's register deps produce counted vmcnt waits (~vmcnt(6)) automatically.
template<int NC>
static __device__ __forceinline__ void run_segment(
    const unsigned short* __restrict__ bp0, const unsigned short* __restrict__ bp1,
    const unsigned short* __restrict__ stA0, const unsigned short* __restrict__ stA1,
    int aBase, int aSwz, f32x4* acc)
{
#define LD_NT(dst, base, c) dst = __builtin_nontemporal_load( \
    reinterpret_cast<const short8*>((base) + (size_t)(c) * 32));
#define STEP(c, P, Q) { \
    const unsigned short* sA_ = (NC == 16 || (c) < 16) ? stA0 : stA1; \
    short8 a_ = *reinterpret_cast<const short8*>(&sA_[(aBase + ((c) & 15) * 32) ^ aSwz]); \
    acc[0] = __builtin_amdgcn_mfma_f32_16x16x32_bf16(a_, P, acc[0], 0, 0, 0); \
    acc[1] = __builtin_amdgcn_mfma_f32_16x16x32_bf16(a_, Q, acc[1], 0, 0, 0); \
    if ((c) + 4 < NC){ LD_NT(P, bp0, (c) + 4) LD_NT(Q, bp1, (c) + 4) } }

  short8 p0, q0, p1, q1, p2, q2, p3, q3;
  LD_NT(p0, bp0, 0) LD_NT(q0, bp1, 0)
  LD_NT(p1, bp0, 1) LD_NT(q1, bp1, 1)
  LD_NT(p2, bp0, 2) LD_NT(q2, bp1, 2)
  LD_NT(p3, bp0, 3) LD_NT(q3, bp1, 3)
#pragma unroll
  for (int c = 0; c < NC; c += 4){
    STEP(c + 0, p0, q0)
    STEP(c + 1, p1, q1)
    STEP(c + 2, p2, q2)
    STEP(c + 3, p3, q3)
  }
#undef LD_NT
#undef STEP
}

// ---------------- persistent per-block RNN: 16 rows through all 80 steps ----------------
__global__ __launch_bounds__(NTHR, 4)
void rnn_persist(const int* __restrict__ tokens,
                 const float* __restrict__ proj,
                 const unsigned short* __restrict__ Wh0t,
                 const unsigned short* __restrict__ W1t,
                 const unsigned short* __restrict__ W2t,
                 const float* __restrict__ b1,
                 const float* __restrict__ b2,
                 const float* __restrict__ Wout,
                 const float* __restrict__ bout,
                 float* __restrict__ out)
{
  __shared__ unsigned short st0[RPB * U];   // 16 KiB each, bf16, XOR-swizzled
  __shared__ unsigned short st1[RPB * U];
  __shared__ unsigned short st2[RPB * U];

  const int tid = threadIdx.x;
  for (int i = tid; i < RPB * U; i += NTHR){ st0[i] = 0; st1[i] = 0; st2[i] = 0; }
  __syncthreads();

  const int lane = tid & 63;
  const int wid  = tid >> 6;          // 16 waves, 32 output cols each
  const int l15  = lane & 15;
  const int khi  = lane >> 4;         // 0..3
  const int n0   = wid * 32;
  const int rowbase = blockIdx.x * RPB;

  // A-frag LDS elem address: row l15, k = kc + khi*8 + j ; swizzle bits 3..5 by row
  const int aBase = l15 * U + khi * 8;
  const int aSwz  = (l15 & 7) << 3;

  // per-lane global bases for B tiles (nf=0 at n0+l15, nf=1 at n0+16+l15), k-contig
  const unsigned short* g0_0 = Wh0t + (size_t)(n0 + l15) * U + khi * 8;
  const unsigned short* g0_1 = g0_0 + (size_t)16 * U;
  const unsigned short* g1_0 = W1t + (size_t)(n0 + l15) * (2 * U) + khi * 8;
  const unsigned short* g1_1 = g1_0 + (size_t)16 * (2 * U);
  const unsigned short* g2_0 = W2t + (size_t)(n0 + l15) * (2 * U) + khi * 8;
  const unsigned short* g2_1 = g2_0 + (size_t)16 * (2 * U);

  const int col0 = n0 + l15;
  const int col1 = n0 + 16 + l15;
  const float b1v0 = b1[col0], b1v1 = b1[col1];
  const float b2v0 = b2[col0], b2v1 = b2[col1];

  f32x4 acc[2];

  for (int t = 0; t < SEQ; ++t){
    // ---------- layer 0: o0 = tanh(proj[tok] + s0 @ Wh0) ----------
    // hoist token + proj gather (L3-latency) so it overlaps the segment below
    int tok0 = tokens[(size_t)(rowbase + khi * 4 + 0) * SEQ + t];
    int tok1 = tokens[(size_t)(rowbase + khi * 4 + 1) * SEQ + t];
    int tok2 = tokens[(size_t)(rowbase + khi * 4 + 2) * SEQ + t];
    int tok3 = tokens[(size_t)(rowbase + khi * 4 + 3) * SEQ + t];
    float pj00 = proj[(size_t)tok0 * U + col0];
    float pj01 = proj[(size_t)tok1 * U + col0];
    float pj02 = proj[(size_t)tok2 * U + col0];
    float pj03 = proj[(size_t)tok3 * U + col0];
    float pj10 = proj[(size_t)tok0 * U + col1];
    float pj11 = proj[(size_t)tok1 * U + col1];
    float pj12 = proj[(size_t)tok2 * U + col1];
    float pj13 = proj[(size_t)tok3 * U + col1];

    acc[0] = 0.0f; acc[1] = 0.0f;
    run_segment<16>(g0_0, g0_1, st0, st0, aBase, aSwz, acc);
    __syncthreads();                 // everyone done reading st0
    {
      const int rr0 = khi * 4;
      st0[((rr0 + 0) * U + col0) ^ (((rr0 + 0) & 7) << 3)] = f2bf(fast_tanh(acc[0][0] + pj00));
      st0[((rr0 + 1) * U + col0) ^ (((rr0 + 1) & 7) << 3)] = f2bf(fast_tanh(acc[0][1] + pj01));
      st0[((rr0 + 2) * U + col0) ^ (((rr0 + 2) & 7) << 3)] = f2bf(fast_tanh(acc[0][2] + pj02));
      st0[((rr0 + 3) * U + col0) ^ (((rr0 + 3) & 7) << 3)] = f2bf(fast_tanh(acc[0][3] + pj03));
      st0[((rr0 + 0) * U + col1) ^ (((rr0 + 0) & 7) << 3)] = f2bf(fast_tanh(acc[1][0] + pj10));
      st0[((rr0 + 1) * U + col1) ^ (((rr0 + 1) & 7) << 3)] = f2bf(fast_tanh(acc[1][1] + pj11));
      st0[((rr0 + 2) * U + col1) ^ (((rr0 + 2) & 7) << 3)] = f2bf(fast_tanh(acc[1][2] + pj12));
      st0[((rr0 + 3) * U + col1) ^ (((rr0 + 3) & 7) << 3)] = f2bf(fast_tanh(acc[1][3] + pj13));
    }
    __syncthreads();

    // ---------- layer 1: o1 = tanh([o0 | s1] @ [Wx1;Wh1] + b1) ----------
    acc[0] = 0.0f; acc[1] = 0.0f;
    run_segment<32>(g1_0, g1_1, st0, st1, aBase, aSwz, acc);
    __syncthreads();
    {
      const int rr0 = khi * 4;
#pragma unroll
      for (int j = 0; j < 4; ++j){
        const int rr = rr0 + j;
        st1[(rr * U + col0) ^ ((rr & 7) << 3)] = f2bf(fast_tanh(acc[0][j] + b1v0));
        st1[(rr * U + col1) ^ ((rr & 7) << 3)] = f2bf(fast_tanh(acc[1][j] + b1v1));
      }
    }
    __syncthreads();

    // ---------- layer 2: o2 = tanh([o1 | s2] @ [Wx2;Wh2] + b2) ----------
    acc[0] = 0.0f; acc[1] = 0.0f;
    run_segment<32>(g2_0, g2_1, st1, st2, aBase, aSwz, acc);
    __syncthreads();
    {
      const int rr0 = khi * 4;
#pragma unroll
      for (int j = 0; j < 4; ++j){
        const int rr = rr0 + j;
        st2[(rr * U + col0) ^ ((rr & 7) << 3)] = f2bf(fast_tanh(acc[0][j] + b2v0));
        st2[(rr * U + col1) ^ ((rr & 7) << 3)] = f2bf(fast_tanh(acc[1][j] + b2v1));
      }
    }
    __syncthreads();
  }

  // ---------- output: sigmoid(s2 @ Wout + bout), one wave per row ----------
  if (wid < RPB){
    const int r = wid;
    float v = 0.0f;
#pragma unroll
    for (int jj = 0; jj < 8; ++jj){
      const int n = lane + jj * 64;
      v += bf2f(st2[(r * U + n) ^ ((r & 7) << 3)]) * Wout[n];
    }
#pragma unroll
    for (int off = 32; off > 0; off >>= 1)
      v += __shfl_down(v, off, 64);
    if (lane == 0)
      out[rowbase + r] = 1.0f / (1.0f + __expf(-(v + bout[0])));
  }
}

extern "C" void kernel_launch(void* const* d_in, const int* in_sizes, int n_in,
                              void* d_out, int out_size, void* d_ws, size_t ws_size,
                              hipStream_t stream){
  (void)in_sizes; (void)n_in; (void)out_size; (void)ws_size;
  const int*   tokens = (const int*)  d_in[0];
  const float* emb  = (const float*)d_in[1];
  const float* Wx0  = (const float*)d_in[2];
  const float* Wh0  = (const float*)d_in[3];
  const float* b0   = (const float*)d_in[4];
  const float* Wx1  = (const float*)d_in[5];
  const float* Wh1  = (const float*)d_in[6];
  const float* b1   = (const float*)d_in[7];
  const float* Wx2  = (const float*)d_in[8];
  const float* Wh2  = (const float*)d_in[9];
  const float* b2   = (const float*)d_in[10];
  const float* Wout = (const float*)d_in[11];
  const float* bout = (const float*)d_in[12];

  char* ws = (char*)d_ws;
  float* proj = (float*)ws;                                   // 10000*512*4  = 20.48 MB
  unsigned short* Wh0t = (unsigned short*)(ws + (size_t)TW * U * 4);
  unsigned short* W1t  = Wh0t + (size_t)U * U;                // [512][1024]
  unsigned short* W2t  = W1t  + (size_t)U * 2 * U;

  proj_kernel<<<TW / 16, 256, 0, stream>>>(emb, Wx0, b0, proj);
  const int tblk = (U * U + 255) / 256;
  transpose_bf16<<<tblk, 256, 0, stream>>>(Wh0, Wh0t, U, U, U,     0);
  transpose_bf16<<<tblk, 256, 0, stream>>>(Wx1, W1t,  U, U, 2 * U, 0);
  transpose_bf16<<<tblk, 256, 0, stream>>>(Wh1, W1t,  U, U, 2 * U, U);
  transpose_bf16<<<tblk, 256, 0, stream>>>(Wx2, W2t,  U, U, 2 * U, 0);
  transpose_bf16<<<tblk, 256, 0, stream>>>(Wh2, W2t,  U, U, 2 * U, U);

  rnn_persist<<<NBLK, NTHR, 0, stream>>>(tokens, proj, Wh0t, W1t, W2t,
                                         b1, b2, Wout, bout, (float*)d_out);
}

// Round 7
// 8357.710 us; speedup vs baseline: 1.0259x; 1.0259x over previous
//
#include <hip/hip_runtime.h>

#define TW    10000
#define EMBD  100
#define SEQ   80
#define U     512
#define BATCH 2048
#define RPB   16
#define NBLK  (BATCH / RPB)   // 128 blocks
#define NTHR  1024            // 16 waves/block

typedef short short8 __attribute__((ext_vector_type(8)));
typedef float f32x4 __attribute__((ext_vector_type(4)));

static __device__ __forceinline__ unsigned short f2bf(float f){
  unsigned int u = __float_as_uint(f);
  u += 0x7fffu + ((u >> 16) & 1u);   // RNE
  return (unsigned short)(u >> 16);
}
static __device__ __forceinline__ float bf2f(unsigned short h){
  return __uint_as_float(((unsigned int)h) << 16);
}
static __device__ __forceinline__ float fast_tanh(float x){
  float e = __expf(2.0f * x);        // inf-safe: saturates to +-1
  return 1.0f - 2.0f / (e + 1.0f);
}

// ---------------- proj[w][n] = b0[n] + sum_e emb[w][e] * Wx0[e][n] ----------------
__global__ void proj_kernel(const float* __restrict__ emb, const float* __restrict__ Wx0,
                            const float* __restrict__ b0, float* __restrict__ proj){
  __shared__ float es[16][EMBD];
  const int w0 = blockIdx.x * 16;
  for (int i = threadIdx.x; i < 16 * EMBD; i += 256)
    es[i / EMBD][i % EMBD] = emb[(size_t)w0 * EMBD + i];
  __syncthreads();
  const int n = threadIdx.x;   // cols n and n+256
  float accA[16], accB[16];
#pragma unroll
  for (int wi = 0; wi < 16; ++wi){ accA[wi] = 0.0f; accB[wi] = 0.0f; }
  for (int e = 0; e < EMBD; ++e){
    const float wv0 = Wx0[(size_t)e * U + n];
    const float wv1 = Wx0[(size_t)e * U + n + 256];
#pragma unroll
    for (int wi = 0; wi < 16; ++wi){
      accA[wi] += es[wi][e] * wv0;
      accB[wi] += es[wi][e] * wv1;
    }
  }
  const float bb0 = b0[n], bb1 = b0[n + 256];
  for (int wi = 0; wi < 16; ++wi){
    proj[(size_t)(w0 + wi) * U + n]       = accA[wi] + bb0;
    proj[(size_t)(w0 + wi) * U + n + 256] = accB[wi] + bb1;
  }
}

// ---------------- dst[n][kOff + k] = bf16(src[k][n]),  src is [K][N] f32 ----------------
__global__ void transpose_bf16(const float* __restrict__ src, unsigned short* __restrict__ dst,
                               int K, int N, int dstLd, int kOff){
  const int idx = blockIdx.x * 256 + threadIdx.x;
  if (idx >= K * N) return;
  const int k = idx % K, n = idx / K;
  dst[(size_t)n * dstLd + kOff + k] = f2bf(src[(size_t)k * N + n]);
}

// One GEMM segment: depth-4 rotating named-register prefetch of B.
// B addressing: uniform SGPR base W + 32-bit VGPR element offsets off0/off1;
// chunk offset c*32 elems = c*64 bytes folds into the load's imm offset.
// Payload: 8 named short8 = 32 VGPRs.
template<int NC>
static __device__ __forceinline__ void run_segment(
    const unsigned short* __restrict__ W, unsigned off0, unsigned off1,
    const unsigned short* __restrict__ stA0, const unsigned short* __restrict__ stA1,
    int aBase, int aSwz, f32x4* acc)
{
#define LDB(dst, off, c) dst = *reinterpret_cast<const short8*>(W + (off) + (unsigned)((c) * 32));
#define STEP(c, P, Q) { \
    const unsigned short* sA_ = (NC == 16 || (c) < 16) ? stA0 : stA1; \
    short8 a_ = *reinterpret_cast<const short8*>(&sA_[(aBase + ((c) & 15) * 32) ^ aSwz]); \
    acc[0] = __builtin_amdgcn_mfma_f32_16x16x32_bf16(a_, P, acc[0], 0, 0, 0); \
    acc[1] = __builtin_amdgcn_mfma_f32_16x16x32_bf16(a_, Q, acc[1], 0, 0, 0); \
    if ((c) + 4 < NC){ LDB(P, off0, (c) + 4) LDB(Q, off1, (c) + 4) } }

  short8 p0, q0, p1, q1, p2, q2, p3, q3;
  LDB(p0, off0, 0) LDB(q0, off1, 0)
  LDB(p1, off0, 1) LDB(q1, off1, 1)
  LDB(p2, off0, 2) LDB(q2, off1, 2)
  LDB(p3, off0, 3) LDB(q3, off1, 3)
#pragma unroll
  for (int c = 0; c < NC; c += 4){
    STEP(c + 0, p0, q0)
    STEP(c + 1, p1, q1)
    STEP(c + 2, p2, q2)
    STEP(c + 3, p3, q3)
  }
#undef LDB
#undef STEP
}

// ---------------- persistent per-block RNN: 16 rows through all 80 steps ----------------
__global__ __launch_bounds__(NTHR)
__attribute__((amdgpu_waves_per_eu(4, 4)))
void rnn_persist(const int* __restrict__ tokens,
                 const float* __restrict__ proj,
                 const unsigned short* __restrict__ Wh0t,
                 const unsigned short* __restrict__ W1t,
                 const unsigned short* __restrict__ W2t,
                 const float* __restrict__ b1,
                 const float* __restrict__ b2,
                 const float* __restrict__ Wout,
                 const float* __restrict__ bout,
                 float* __restrict__ out)
{
  __shared__ unsigned short st0[RPB * U];   // 16 KiB each, bf16, XOR-swizzled
  __shared__ unsigned short st1[RPB * U];
  __shared__ unsigned short st2[RPB * U];

  const int tid = threadIdx.x;
  for (int i = tid; i < RPB * U; i += NTHR){ st0[i] = 0; st1[i] = 0; st2[i] = 0; }
  __syncthreads();

  const int lane = tid & 63;
  const int wid  = tid >> 6;          // 16 waves, 32 output cols each
  const int l15  = lane & 15;
  const int khi  = lane >> 4;         // 0..3
  const int n0   = wid * 32;
  const int rowbase = blockIdx.x * RPB;

  // A-frag LDS elem address: row l15, k = kc + khi*8 + j ; swizzle bits 3..5 by row
  const int aBase = l15 * U + khi * 8;
  const int aSwz  = (l15 & 7) << 3;

  // B element offsets: tile0 col = n0+l15, tile1 col = n0+16+l15 (k-contiguous rows)
  const unsigned off512_0  = (unsigned)(n0 + l15) * U + (unsigned)(khi * 8);
  const unsigned off512_1  = off512_0 + 16u * U;
  const unsigned off1024_0 = (unsigned)(n0 + l15) * (2 * U) + (unsigned)(khi * 8);
  const unsigned off1024_1 = off1024_0 + 16u * (2 * U);

  const int col0 = n0 + l15;
  const int col1 = n0 + 16 + l15;
  const float b1v0 = b1[col0], b1v1 = b1[col1];
  const float b2v0 = b2[col0], b2v1 = b2[col1];

  f32x4 acc[2];

  for (int t = 0; t < SEQ; ++t){
    // ---------- layer 0: o0 = tanh(proj[tok] + s0 @ Wh0) ----------
    acc[0] = 0.0f; acc[1] = 0.0f;
    run_segment<16>(Wh0t, off512_0, off512_1, st0, st0, aBase, aSwz, acc);
    __syncthreads();                 // everyone done reading st0
    {
      const int rr0 = khi * 4;
#pragma unroll
      for (int j = 0; j < 4; ++j){
        const int rr = rr0 + j;
        const int tk = tokens[(size_t)(rowbase + rr) * SEQ + t];
        const float z0 = acc[0][j] + proj[(size_t)tk * U + col0];
        const float z1 = acc[1][j] + proj[(size_t)tk * U + col1];
        st0[(rr * U + col0) ^ ((rr & 7) << 3)] = f2bf(fast_tanh(z0));
        st0[(rr * U + col1) ^ ((rr & 7) << 3)] = f2bf(fast_tanh(z1));
      }
    }
    __syncthreads();

    // ---------- layer 1: o1 = tanh([o0 | s1] @ [Wx1;Wh1] + b1) ----------
    acc[0] = 0.0f; acc[1] = 0.0f;
    run_segment<32>(W1t, off1024_0, off1024_1, st0, st1, aBase, aSwz, acc);
    __syncthreads();
    {
      const int rr0 = khi * 4;
#pragma unroll
      for (int j = 0; j < 4; ++j){
        const int rr = rr0 + j;
        st1[(rr * U + col0) ^ ((rr & 7) << 3)] = f2bf(fast_tanh(acc[0][j] + b1v0));
        st1[(rr * U + col1) ^ ((rr & 7) << 3)] = f2bf(fast_tanh(acc[1][j] + b1v1));
      }
    }
    __syncthreads();

    // ---------- layer 2: o2 = tanh([o1 | s2] @ [Wx2;Wh2] + b2) ----------
    acc[0] = 0.0f; acc[1] = 0.0f;
    run_segment<32>(W2t, off1024_0, off1024_1, st1, st2, aBase, aSwz, acc);
    __syncthreads();
    {
      const int rr0 = khi * 4;
#pragma unroll
      for (int j = 0; j < 4; ++j){
        const int rr = rr0 + j;
        st2[(rr * U + col0) ^ ((rr & 7) << 3)] = f2bf(fast_tanh(acc[0][j] + b2v0));
        st2[(rr * U + col1) ^ ((rr & 7) << 3)] = f2bf(fast_tanh(acc[1][j] + b2v1));
      }
    }
    __syncthreads();
  }

  // ---------- output: sigmoid(s2 @ Wout + bout), one wave per row ----------
  if (wid < RPB){
    const int r = wid;
    float v = 0.0f;
#pragma unroll
    for (int jj = 0; jj < 8; ++jj){
      const int n = lane + jj * 64;
      v += bf2f(st2[(r * U + n) ^ ((r & 7) << 3)]) * Wout[n];
    }
#pragma unroll
    for (int off = 32; off > 0; off >>= 1)
      v += __shfl_down(v, off, 64);
    if (lane == 0)
      out[rowbase + r] = 1.0f / (1.0f + __expf(-(v + bout[0])));
  }
}

extern "C" void kernel_launch(void* const* d_in, const int* in_sizes, int n_in,
                              void* d_out, int out_size, void* d_ws, size_t ws_size,
                              hipStream_t stream){
  (void)in_sizes; (void)n_in; (void)out_size; (void)ws_size;
  const int*   tokens = (const int*)  d_in[0];
  const float* emb  = (const float*)d_in[1];
  const float* Wx0  = (const float*)d_in[2];
  const float* Wh0  = (const float*)d_in[3];
  const float* b0   = (const float*)d_in[4];
  const float* Wx1  = (const float*)d_in[5];
  const float* Wh1  = (const float*)d_in[6];
  const float* b1   = (const float*)d_in[7];
  const float* Wx2  = (const float*)d_in[8];
  const float* Wh2  = (const float*)d_in[9];
  const float* b2   = (const float*)d_in[10];
  const float* Wout = (const float*)d_in[11];
  const float* bout = (const float*)d_in[12];

  char* ws = (char*)d_ws;
  float* proj = (float*)ws;                                   // 10000*512*4  = 20.48 MB
  unsigned short* Wh0t = (unsigned short*)(ws + (size_t)TW * U * 4);
  unsigned short* W1t  = Wh0t + (size_t)U * U;                // [512][1024]
  unsigned short* W2t  = W1t  + (size_t)U * 2 * U;

  proj_kernel<<<TW / 16, 256, 0, stream>>>(emb, Wx0, b0, proj);
  const int tblk = (U * U + 255) / 256;
  transpose_bf16<<<tblk, 256, 0, stream>>>(Wh0, Wh0t, U, U, U,     0);
  transpose_bf16<<<tblk, 256, 0, stream>>>(Wx1, W1t,  U, U, 2 * U, 0);
  transpose_bf16<<<tblk, 256, 0, stream>>>(Wh1, W1t,  U, U, 2 * U, U);
  transpose_bf16<<<tblk, 256, 0, stream>>>(Wx2, W2t,  U, U, 2 * U, 0);
  transpose_bf16<<<tblk, 256, 0, stream>>>(Wh2, W2t,  U, U, 2 * U, U);

  rnn_persist<<<NBLK, NTHR, 0, stream>>>(tokens, proj, Wh0t, W1t, W2t,
                                         b1, b2, Wout, bout, (float*)d_out);
}

// Round 8
// 7081.363 us; speedup vs baseline: 1.2109x; 1.1802x over previous
//
#include <hip/hip_runtime.h>

#define TW    10000
#define EMBD  100
#define SEQ   80
#define U     512
#define BATCH 2048
#define RPB   16
#define NBLK  (BATCH / RPB)   // 128 blocks
#define NTHR  1024            // 16 waves/block
#define PK0   544             // padded pitch for K=512 weights (breaks pow2 stride)
#define PK1   1056            // padded pitch for K=1024 weights

typedef short short8 __attribute__((ext_vector_type(8)));
typedef float f32x4 __attribute__((ext_vector_type(4)));

static __device__ __forceinline__ unsigned short f2bf(float f){
  unsigned int u = __float_as_uint(f);
  u += 0x7fffu + ((u >> 16) & 1u);   // RNE
  return (unsigned short)(u >> 16);
}
static __device__ __forceinline__ float bf2f(unsigned short h){
  return __uint_as_float(((unsigned int)h) << 16);
}
static __device__ __forceinline__ float fast_tanh(float x){
  float e = __expf(2.0f * x);        // inf-safe: saturates to +-1
  return 1.0f - 2.0f / (e + 1.0f);
}

// ---------------- proj[w][n] = b0[n] + sum_e emb[w][e] * Wx0[e][n] ----------------
__global__ void proj_kernel(const float* __restrict__ emb, const float* __restrict__ Wx0,
                            const float* __restrict__ b0, float* __restrict__ proj){
  __shared__ float es[16][EMBD];
  const int w0 = blockIdx.x * 16;
  for (int i = threadIdx.x; i < 16 * EMBD; i += 256)
    es[i / EMBD][i % EMBD] = emb[(size_t)w0 * EMBD + i];
  __syncthreads();
  const int n = threadIdx.x;   // cols n and n+256
  float accA[16], accB[16];
#pragma unroll
  for (int wi = 0; wi < 16; ++wi){ accA[wi] = 0.0f; accB[wi] = 0.0f; }
  for (int e = 0; e < EMBD; ++e){
    const float wv0 = Wx0[(size_t)e * U + n];
    const float wv1 = Wx0[(size_t)e * U + n + 256];
#pragma unroll
    for (int wi = 0; wi < 16; ++wi){
      accA[wi] += es[wi][e] * wv0;
      accB[wi] += es[wi][e] * wv1;
    }
  }
  const float bb0 = b0[n], bb1 = b0[n + 256];
  for (int wi = 0; wi < 16; ++wi){
    proj[(size_t)(w0 + wi) * U + n]       = accA[wi] + bb0;
    proj[(size_t)(w0 + wi) * U + n + 256] = accB[wi] + bb1;
  }
}

// -------- dst[n][kOff + k] = bf16(src[k][n]), src [K][N] f32, dst pitch-padded --------
__global__ void transpose_bf16(const float* __restrict__ src, unsigned short* __restrict__ dst,
                               int K, int N, int dstPitch, int kOff){
  const int idx = blockIdx.x * 256 + threadIdx.x;
  if (idx >= K * N) return;
  const int k = idx % K, n = idx / K;
  dst[(size_t)n * dstPitch + kOff + k] = f2bf(src[(size_t)k * N + n]);
}

// One GEMM segment: B direct from global (nt hint), rotated chunk order.
// voff0/voff1 = per-lane element offsets of the two col-tiles (incl khi*8),
// chunk c adds c*32 elems. A from swizzled state LDS. Register-light.
template<int NC>
static __device__ __forceinline__ void run_segment(
    const unsigned short* __restrict__ W, unsigned voff0, unsigned voff1,
    const unsigned short* __restrict__ stA0, const unsigned short* __restrict__ stA1,
    int aBase, int aSwz, int rot, f32x4* acc)
{
#pragma unroll 8
  for (int i = 0; i < NC; ++i){
    const int c = (i + rot) & (NC - 1);
    const unsigned short* sA_ = (NC == 16 || c < 16) ? stA0 : stA1;
    short8 a = *reinterpret_cast<const short8*>(&sA_[(aBase + (c & 15) * 32) ^ aSwz]);
    short8 b0 = __builtin_nontemporal_load(
        reinterpret_cast<const short8*>(W + voff0 + (unsigned)(c * 32)));
    short8 b1 = __builtin_nontemporal_load(
        reinterpret_cast<const short8*>(W + voff1 + (unsigned)(c * 32)));
    acc[0] = __builtin_amdgcn_mfma_f32_16x16x32_bf16(a, b0, acc[0], 0, 0, 0);
    acc[1] = __builtin_amdgcn_mfma_f32_16x16x32_bf16(a, b1, acc[1], 0, 0, 0);
  }
}

// ---------------- persistent per-block RNN: 16 rows through all 80 steps ----------------
__global__ __launch_bounds__(NTHR, 4)
void rnn_persist(const int* __restrict__ tokens,
                 const float* __restrict__ proj,
                 const unsigned short* __restrict__ Wh0t,
                 const unsigned short* __restrict__ W1t,
                 const unsigned short* __restrict__ W2t,
                 const float* __restrict__ b1,
                 const float* __restrict__ b2,
                 const float* __restrict__ Wout,
                 const float* __restrict__ bout,
                 float* __restrict__ out)
{
  __shared__ unsigned short st0[RPB * U];   // 16 KiB each, bf16, XOR-swizzled
  __shared__ unsigned short st1[RPB * U];
  __shared__ unsigned short st2[RPB * U];

  const int tid = threadIdx.x;
  for (int i = tid; i < RPB * U; i += NTHR){ st0[i] = 0; st1[i] = 0; st2[i] = 0; }
  __syncthreads();

  const int lane = tid & 63;
  const int wid  = tid >> 6;          // 16 waves, 32 output cols each
  const int l15  = lane & 15;
  const int khi  = lane >> 4;         // 0..3
  const int n0   = wid * 32;
  const int rowbase = blockIdx.x * RPB;

  // rotated chunk starts: de-sync the 2048 concurrent weight streams
  const int rot16 = (wid + blockIdx.x * 3) & 15;
  const int rot32 = (wid * 2 + blockIdx.x * 5) & 31;

  // A-frag LDS elem address: row l15, k = kc + khi*8 + j ; swizzle bits 3..5 by row
  const int aBase = l15 * U + khi * 8;
  const int aSwz  = (l15 & 7) << 3;

  // B element offsets (padded pitch): tile0 col = n0+l15, tile1 col = n0+16+l15
  const unsigned offA0 = (unsigned)(n0 + l15) * PK0 + (unsigned)(khi * 8);
  const unsigned offA1 = offA0 + 16u * PK0;
  const unsigned offB0 = (unsigned)(n0 + l15) * PK1 + (unsigned)(khi * 8);
  const unsigned offB1 = offB0 + 16u * PK1;

  const int col0 = n0 + l15;
  const int col1 = n0 + 16 + l15;
  const float b1v0 = b1[col0], b1v1 = b1[col1];
  const float b2v0 = b2[col0], b2v1 = b2[col1];

  f32x4 acc[2];

  for (int t = 0; t < SEQ; ++t){
    // ---------- layer 0: o0 = tanh(proj[tok] + s0 @ Wh0) ----------
    acc[0] = 0.0f; acc[1] = 0.0f;
    run_segment<16>(Wh0t, offA0, offA1, st0, st0, aBase, aSwz, rot16, acc);
    __syncthreads();                 // everyone done reading st0
    {
      const int rr0 = khi * 4;
#pragma unroll
      for (int j = 0; j < 4; ++j){
        const int rr = rr0 + j;
        const int tk = tokens[(size_t)(rowbase + rr) * SEQ + t];
        const float z0 = acc[0][j] + proj[(size_t)tk * U + col0];
        const float z1 = acc[1][j] + proj[(size_t)tk * U + col1];
        st0[(rr * U + col0) ^ ((rr & 7) << 3)] = f2bf(fast_tanh(z0));
        st0[(rr * U + col1) ^ ((rr & 7) << 3)] = f2bf(fast_tanh(z1));
      }
    }
    __syncthreads();

    // ---------- layer 1: o1 = tanh([o0 | s1] @ [Wx1;Wh1] + b1) ----------
    acc[0] = 0.0f; acc[1] = 0.0f;
    run_segment<32>(W1t, offB0, offB1, st0, st1, aBase, aSwz, rot32, acc);
    __syncthreads();
    {
      const int rr0 = khi * 4;
#pragma unroll
      for (int j = 0; j < 4; ++j){
        const int rr = rr0 + j;
        st1[(rr * U + col0) ^ ((rr & 7) << 3)] = f2bf(fast_tanh(acc[0][j] + b1v0));
        st1[(rr * U + col1) ^ ((rr & 7) << 3)] = f2bf(fast_tanh(acc[1][j] + b1v1));
      }
    }
    __syncthreads();

    // ---------- layer 2: o2 = tanh([o1 | s2] @ [Wx2;Wh2] + b2) ----------
    acc[0] = 0.0f; acc[1] = 0.0f;
    run_segment<32>(W2t, offB0, offB1, st1, st2, aBase, aSwz, rot32, acc);
    __syncthreads();
    {
      const int rr0 = khi * 4;
#pragma unroll
      for (int j = 0; j < 4; ++j){
        const int rr = rr0 + j;
        st2[(rr * U + col0) ^ ((rr & 7) << 3)] = f2bf(fast_tanh(acc[0][j] + b2v0));
        st2[(rr * U + col1) ^ ((rr & 7) << 3)] = f2bf(fast_tanh(acc[1][j] + b2v1));
      }
    }
    __syncthreads();
  }

  // ---------- output: sigmoid(s2 @ Wout + bout), one wave per row ----------
  if (wid < RPB){
    const int r = wid;
    float v = 0.0f;
#pragma unroll
    for (int jj = 0; jj < 8; ++jj){
      const int n = lane + jj * 64;
      v += bf2f(st2[(r * U + n) ^ ((r & 7) << 3)]) * Wout[n];
    }
#pragma unroll
    for (int off = 32; off > 0; off >>= 1)
      v += __shfl_down(v, off, 64);
    if (lane == 0)
      out[rowbase + r] = 1.0f / (1.0f + __expf(-(v + bout[0])));
  }
}

extern "C" void kernel_launch(void* const* d_in, const int* in_sizes, int n_in,
                              void* d_out, int out_size, void* d_ws, size_t ws_size,
                              hipStream_t stream){
  (void)in_sizes; (void)n_in; (void)out_size; (void)ws_size;
  const int*   tokens = (const int*)  d_in[0];
  const float* emb  = (const float*)d_in[1];
  const float* Wx0  = (const float*)d_in[2];
  const float* Wh0  = (const float*)d_in[3];
  const float* b0   = (const float*)d_in[4];
  const float* Wx1  = (const float*)d_in[5];
  const float* Wh1  = (const float*)d_in[6];
  const float* b1   = (const float*)d_in[7];
  const float* Wx2  = (const float*)d_in[8];
  const float* Wh2  = (const float*)d_in[9];
  const float* b2   = (const float*)d_in[10];
  const float* Wout = (const float*)d_in[11];
  const float* bout = (const float*)d_in[12];

  char* ws = (char*)d_ws;
  float* proj = (float*)ws;                                   // 10000*512*4  = 20.48 MB
  unsigned short* Wh0t = (unsigned short*)(ws + (size_t)TW * U * 4);
  unsigned short* W1t  = Wh0t + (size_t)U * PK0;              // [512][1056] padded
  unsigned short* W2t  = W1t  + (size_t)U * PK1;

  proj_kernel<<<TW / 16, 256, 0, stream>>>(emb, Wx0, b0, proj);
  const int tblk = (U * U + 255) / 256;
  transpose_bf16<<<tblk, 256, 0, stream>>>(Wh0, Wh0t, U, U, PK0, 0);
  transpose_bf16<<<tblk, 256, 0, stream>>>(Wx1, W1t,  U, U, PK1, 0);
  transpose_bf16<<<tblk, 256, 0, stream>>>(Wh1, W1t,  U, U, PK1, U);
  transpose_bf16<<<tblk, 256, 0, stream>>>(Wx2, W2t,  U, U, PK1, 0);
  transpose_bf16<<<tblk, 256, 0, stream>>>(Wh2, W2t,  U, U, PK1, U);

  rnn_persist<<<NBLK, NTHR, 0, stream>>>(tokens, proj, Wh0t, W1t, W2t,
                                         b1, b2, Wout, bout, (float*)d_out);
}